// Round 1
// baseline (341.004 us; speedup 1.0000x reference)
//
#include <hip/hip_runtime.h>
#include <hip/hip_bf16.h>
#include <math.h>

#define N_POINTS 32
#define SPACE_DIM 16
#define EMB 512
#define EPS_F 0.1f
#define INV_EPS 10.0f
#define THRESH 0.1f
#define MAX_ITER 10

// ---------------- GEMM: Z = X @ W  (MxK fp32 @ KxN fp32) ----------------
#define BM 64
#define BN 64
#define BK 16

__global__ __launch_bounds__(256) void gemm_f32(
    const float* __restrict__ X, const float* __restrict__ W,
    float* __restrict__ Z, int M, int K, int N)
{
    __shared__ float As[BM][BK + 1];
    __shared__ float Bs[BK][BN + 1];

    int m0 = blockIdx.x * BM, n0 = blockIdx.y * BN;
    int t = threadIdx.x;
    int tx = t & 15, ty = t >> 4;  // 16x16 thread grid, each does 4x4

    float acc[4][4] = {};

    for (int k0 = 0; k0 < K; k0 += BK) {
        {   // A tile: 64 rows x 16 k
            int row = t >> 2;
            int kk  = (t & 3) * 4;
            int gm = m0 + row;
            float4 va = make_float4(0.f, 0.f, 0.f, 0.f);
            if (gm < M) va = *(const float4*)&X[(size_t)gm * K + k0 + kk];
            As[row][kk + 0] = va.x; As[row][kk + 1] = va.y;
            As[row][kk + 2] = va.z; As[row][kk + 3] = va.w;
        }
        {   // B tile: 16 k x 64 n
            int kk = t >> 4;
            int nn = (t & 15) * 4;
            float4 vb = *(const float4*)&W[(size_t)(k0 + kk) * N + n0 + nn];
            Bs[kk][nn + 0] = vb.x; Bs[kk][nn + 1] = vb.y;
            Bs[kk][nn + 2] = vb.z; Bs[kk][nn + 3] = vb.w;
        }
        __syncthreads();
        #pragma unroll
        for (int kk = 0; kk < BK; ++kk) {
            float a[4], b[4];
            #pragma unroll
            for (int i = 0; i < 4; ++i) a[i] = As[ty * 4 + i][kk];
            #pragma unroll
            for (int j = 0; j < 4; ++j) b[j] = Bs[kk][tx * 4 + j];
            #pragma unroll
            for (int i = 0; i < 4; ++i)
                #pragma unroll
                for (int j = 0; j < 4; ++j)
                    acc[i][j] = fmaf(a[i], b[j], acc[i][j]);
        }
        __syncthreads();
    }
    #pragma unroll
    for (int i = 0; i < 4; ++i) {
        int gm = m0 + ty * 4 + i;
        if (gm < M) {
            *(float4*)&Z[(size_t)gm * N + n0 + tx * 4] =
                make_float4(acc[i][0], acc[i][1], acc[i][2], acc[i][3]);
        }
    }
}

// ---------------- Sinkhorn per edge: 1 wave per edge ----------------
// mode 0: run MAX_ITER iterations, write err_part[it*(2*nE)+b] = sum_i |du_i|
// mode 1: read err_mean[2*MAX_ITER], derive T, run T iterations, write energy[b]
__global__ __launch_bounds__(64) void sinkhorn_kernel(
    const float* __restrict__ Z,
    const int* __restrict__ ep, const int* __restrict__ en,
    int nE,
    float* __restrict__ err_part,
    const float* __restrict__ err_mean,
    float* __restrict__ energy,
    int mode)
{
    __shared__ float sa[EMB], sb[EMB];
    __shared__ float C[N_POINTS][N_POINTS + 1];
    __shared__ float su[N_POINTS], sv[N_POINTS], sun[N_POINTS];

    int b = blockIdx.x;
    int side = (b >= nE) ? 1 : 0;
    int e = b - side * nE;
    const int* edges = side ? en : ep;
    int nx = edges[e];
    int ny = edges[e + nE];

    int t = threadIdx.x;

    const float* za = Z + (size_t)nx * EMB;
    const float* zb = Z + (size_t)ny * EMB;
    for (int idx = t; idx < EMB; idx += 64) {
        sa[idx] = za[idx];
        sb[idx] = zb[idx];
    }
    if (t < N_POINTS) { su[t] = 0.f; sv[t] = 0.f; }
    __syncthreads();

    // C[i][j] = ||a_i - b_j||^2 ; thread t: row i = t>>1, cols (t&1)*16..+15
    {
        int i = t >> 1;
        int j0 = (t & 1) * 16;
        #pragma unroll
        for (int jj = 0; jj < 16; ++jj) {
            int j = j0 + jj;
            float s = 0.f;
            #pragma unroll
            for (int d = 0; d < SPACE_DIM; ++d) {
                float diff = sa[i * SPACE_DIM + d] - sb[j * SPACE_DIM + d];
                s = fmaf(diff, diff, s);
            }
            C[i][j] = s;
        }
    }
    __syncthreads();

    int niter = MAX_ITER;
    if (mode == 1) {
        for (int it = 0; it < MAX_ITER; ++it) {
            if (err_mean[side * MAX_ITER + it] < THRESH) { niter = it + 1; break; }
        }
    }

    const float logmu = logf(1.0f / 32.0f + 1e-8f);  // == lognu (P1==P2)

    int lane_i = t & 31;   // row (row pass) / col (col pass)
    int h = t >> 5;        // which half of the 32-length reduction axis
    int r0 = h * 16;

    for (int it = 0; it < niter; ++it) {
        // ---- row pass: update u ----
        float ui = su[lane_i];
        float raw[16];
        float mx = -INFINITY;
        #pragma unroll
        for (int jj = 0; jj < 16; ++jj) {
            int j = r0 + jj;
            float r = (ui + sv[j] - C[lane_i][j]) * INV_EPS;
            raw[jj] = r;
            mx = fmaxf(mx, r);
        }
        mx = fmaxf(mx, __shfl_xor(mx, 32));
        float sm = 0.f;
        #pragma unroll
        for (int jj = 0; jj < 16; ++jj) sm += expf(raw[jj] - mx);
        sm += __shfl_xor(sm, 32);
        float lse = mx + logf(sm);
        float un = fmaf(EPS_F, logmu - lse, ui);
        if (h == 0) sun[lane_i] = un;

        float du = (h == 0) ? fabsf(un - ui) : 0.f;
        #pragma unroll
        for (int m = 1; m < 64; m <<= 1) du += __shfl_xor(du, m);
        if (mode == 0 && t == 0) err_part[it * (2 * nE) + b] = du;
        __syncthreads();   // sun visible

        // ---- col pass: update v (uses u_new) ----
        float vj = sv[lane_i];
        mx = -INFINITY;
        #pragma unroll
        for (int ii = 0; ii < 16; ++ii) {
            int i = r0 + ii;
            float r = (sun[i] + vj - C[i][lane_i]) * INV_EPS;
            raw[ii] = r;
            mx = fmaxf(mx, r);
        }
        mx = fmaxf(mx, __shfl_xor(mx, 32));
        sm = 0.f;
        #pragma unroll
        for (int ii = 0; ii < 16; ++ii) sm += expf(raw[ii] - mx);
        sm += __shfl_xor(sm, 32);
        lse = mx + logf(sm);
        float vn = fmaf(EPS_F, logmu - lse, vj);
        __syncthreads();   // everyone done reading sv/sun
        if (h == 0) { sv[lane_i] = vn; su[lane_i] = sun[lane_i]; }
        __syncthreads();
    }

    if (mode == 1) {
        // cost = sum_{i,j} exp(M(u,v)) * C
        int i = t >> 1;
        int j0 = (t & 1) * 16;
        float ui = su[i];
        float acc = 0.f;
        #pragma unroll
        for (int jj = 0; jj < 16; ++jj) {
            int j = j0 + jj;
            float Cij = C[i][j];
            float r = (ui + sv[j] - Cij) * INV_EPS;
            acc = fmaf(expf(r), Cij, acc);
        }
        #pragma unroll
        for (int m = 1; m < 64; m <<= 1) acc += __shfl_xor(acc, m);
        if (t == 0) {
            float cost = acc;                 // energy = -cost
            energy[b] = side ? expf(-cost)    // exp(neg_energy)
                             : cost * cost;   // pos_energy^2
        }
    }
}

// ---------------- err reduction: 20 blocks, deterministic ----------------
__global__ __launch_bounds__(256) void err_reduce(
    const float* __restrict__ err_part, float* __restrict__ err_mean, int nE)
{
    int side = blockIdx.x / MAX_ITER;
    int it = blockIdx.x - side * MAX_ITER;
    const float* p = err_part + it * (2 * nE) + side * nE;
    float s = 0.f;
    for (int idx = threadIdx.x; idx < nE; idx += 256) s += p[idx];
    __shared__ float red[256];
    red[threadIdx.x] = s;
    __syncthreads();
    for (int stride = 128; stride > 0; stride >>= 1) {
        if (threadIdx.x < stride) red[threadIdx.x] += red[threadIdx.x + stride];
        __syncthreads();
    }
    if (threadIdx.x == 0) err_mean[side * MAX_ITER + it] = red[0] / (float)nE;
}

// ---------------- final loss: mean(pos^2 + exp(neg)) ----------------
__global__ __launch_bounds__(256) void loss_reduce(
    const float* __restrict__ energy, float* __restrict__ out, int nE)
{
    float s = 0.f;
    for (int idx = threadIdx.x; idx < 2 * nE; idx += 256) s += energy[idx];
    __shared__ float red[256];
    red[threadIdx.x] = s;
    __syncthreads();
    for (int stride = 128; stride > 0; stride >>= 1) {
        if (threadIdx.x < stride) red[threadIdx.x] += red[threadIdx.x + stride];
        __syncthreads();
    }
    if (threadIdx.x == 0) out[0] = red[0] / (float)nE;
}

extern "C" void kernel_launch(void* const* d_in, const int* in_sizes, int n_in,
                              void* d_out, int out_size, void* d_ws, size_t ws_size,
                              hipStream_t stream)
{
    const float* X = (const float*)d_in[0];
    const float* W = (const float*)d_in[1];
    const int* ep = (const int*)d_in[2];
    const int* en = (const int*)d_in[3];
    float* out = (float*)d_out;

    int K = in_sizes[1] / EMB;     // 256
    int M = in_sizes[0] / K;       // 10000
    int nE = in_sizes[2] / 2;      // 4096

    float* ws = (float*)d_ws;
    float* Z = ws;                                        // M*EMB
    float* err_part = Z + (size_t)M * EMB;                // MAX_ITER * 2*nE
    float* err_mean = err_part + (size_t)MAX_ITER * 2 * nE; // 32 (20 used)
    float* energy = err_mean + 32;                        // 2*nE

    dim3 gg((M + BM - 1) / BM, EMB / BN);
    gemm_f32<<<gg, 256, 0, stream>>>(X, W, Z, M, K, EMB);

    sinkhorn_kernel<<<2 * nE, 64, 0, stream>>>(Z, ep, en, nE,
                                               err_part, nullptr, nullptr, 0);
    err_reduce<<<2 * MAX_ITER, 256, 0, stream>>>(err_part, err_mean, nE);
    sinkhorn_kernel<<<2 * nE, 64, 0, stream>>>(Z, ep, en, nE,
                                               nullptr, err_mean, energy, 1);
    loss_reduce<<<1, 256, 0, stream>>>(energy, out, nE);
}

// Round 2
// 184.793 us; speedup vs baseline: 1.8453x; 1.8453x over previous
//
#include <hip/hip_runtime.h>
#include <hip/hip_bf16.h>
#include <math.h>

#define N_POINTS 32
#define SPACE_DIM 16
#define EMB 512
#define THRESH 0.1f
#define MAX_ITER 10

// ---------------- GEMM: Z = X @ W  (MxK fp32 @ KxN fp32) ----------------
// A-tile stored TRANSPOSED in LDS so both fragment loads are aligned b128.
#define BM 64
#define BN 64
#define BK 16
#define LDP 68   // padded stride (floats): 272 B, 16B-aligned, breaks bank patterns

__global__ __launch_bounds__(256) void gemm_f32(
    const float* __restrict__ X, const float* __restrict__ W,
    float* __restrict__ Z, int M, int K, int N)
{
    __shared__ float As[BK][LDP];   // [k][m]
    __shared__ float Bs[BK][LDP];   // [k][n]

    int m0 = blockIdx.x * BM, n0 = blockIdx.y * BN;
    int t = threadIdx.x;
    int tx = t & 15, ty = t >> 4;      // 16x16 threads, each 4x4 output

    int arow = t >> 2;                 // 0..63  (m within tile)
    int akc  = (t & 3) * 4;            // 0,4,8,12 (k within tile)
    int bkk  = t >> 4;                 // 0..15  (k within tile)
    int bnn  = (t & 15) * 4;           // 0..60  (n within tile)

    float acc[4][4] = {};

    for (int k0 = 0; k0 < K; k0 += BK) {
        {   // A tile: 64 m x 16 k, stored transposed
            int gm = m0 + arow;
            float4 va = make_float4(0.f, 0.f, 0.f, 0.f);
            if (gm < M) va = *(const float4*)&X[(size_t)gm * K + k0 + akc];
            As[akc + 0][arow] = va.x;
            As[akc + 1][arow] = va.y;
            As[akc + 2][arow] = va.z;
            As[akc + 3][arow] = va.w;
        }
        {   // B tile: 16 k x 64 n
            float4 vb = *(const float4*)&W[(size_t)(k0 + bkk) * N + n0 + bnn];
            *(float4*)&Bs[bkk][bnn] = vb;
        }
        __syncthreads();
        #pragma unroll
        for (int kk = 0; kk < BK; ++kk) {
            float4 a = *(const float4*)&As[kk][ty * 4];
            float4 b = *(const float4*)&Bs[kk][tx * 4];
            float av[4] = {a.x, a.y, a.z, a.w};
            float bv[4] = {b.x, b.y, b.z, b.w};
            #pragma unroll
            for (int i = 0; i < 4; ++i)
                #pragma unroll
                for (int j = 0; j < 4; ++j)
                    acc[i][j] = fmaf(av[i], bv[j], acc[i][j]);
        }
        __syncthreads();
    }
    #pragma unroll
    for (int i = 0; i < 4; ++i) {
        int gm = m0 + ty * 4 + i;
        if (gm < M) {
            *(float4*)&Z[(size_t)gm * N + n0 + tx * 4] =
                make_float4(acc[i][0], acc[i][1], acc[i][2], acc[i][3]);
        }
    }
}

// ---------------- Fused Sinkhorn: 1 wave per edge, register-resident ------
// Scaled variables: U=u/eps, V=v/eps, Crow = -10*C (so M = U + V + Crow).
// u cancels in row-lse; 10*eps == 1 so updates are pure adds.
// Writes per-iteration err sums AND per-iteration costs; no second pass.
__global__ __launch_bounds__(64) void sinkhorn_fused(
    const float* __restrict__ Z,
    const int* __restrict__ ep, const int* __restrict__ en,
    int nE,
    float* __restrict__ err_part,   // [MAX_ITER][2nE]
    float* __restrict__ cost_all)   // [MAX_ITER][2nE]
{
    __shared__ float sb[32 * 20];       // b point rows, padded stride 20
    __shared__ float csh[32 * 33];      // transpose staging for C

    int b = blockIdx.x;
    int side = (b >= nE) ? 1 : 0;
    int e = b - side * nE;
    const int* edges = side ? en : ep;
    int nx = edges[e];
    int ny = edges[e + nE];

    int t = threadIdx.x;
    int c = t & 31;          // this lane's row (row pass) / col (col pass)
    int h = t >> 5;          // which 16-wide half of the reduction axis
    int r0 = h * 16;

    const float* za = Z + (size_t)nx * EMB;
    const float* zb = Z + (size_t)ny * EMB;

    // stage b rows into padded LDS (broadcast-friendly reads later)
    for (int idx = t; idx < EMB; idx += 64)
        sb[(idx >> 4) * 20 + (idx & 15)] = zb[idx];

    // own a-row in registers
    float areg[16];
    {
        const float4* zr = (const float4*)(za + c * SPACE_DIM);
        float4 v0 = zr[0], v1 = zr[1], v2 = zr[2], v3 = zr[3];
        areg[0] = v0.x; areg[1] = v0.y; areg[2] = v0.z; areg[3] = v0.w;
        areg[4] = v1.x; areg[5] = v1.y; areg[6] = v1.z; areg[7] = v1.w;
        areg[8] = v2.x; areg[9] = v2.y; areg[10] = v2.z; areg[11] = v2.w;
        areg[12] = v3.x; areg[13] = v3.y; areg[14] = v3.z; areg[15] = v3.w;
    }
    __syncthreads();

    // Crow[jj] = -10 * ||a_c - b_{r0+jj}||^2
    float Crow[16];
    #pragma unroll
    for (int jj = 0; jj < 16; ++jj) {
        int j = r0 + jj;
        float s = 0.f;
        #pragma unroll
        for (int d = 0; d < SPACE_DIM; ++d) {
            float diff = areg[d] - sb[j * 20 + d];
            s = fmaf(diff, diff, s);
        }
        Crow[jj] = -10.f * s;
    }
    // transpose through LDS to get the column fragment
    #pragma unroll
    for (int jj = 0; jj < 16; ++jj)
        csh[c * 33 + (r0 + jj)] = Crow[jj];
    __syncthreads();
    float Ccol[16];
    #pragma unroll
    for (int ii = 0; ii < 16; ++ii)
        Ccol[ii] = csh[(r0 + ii) * 33 + c];

    const float logmu = logf(1.0f / 32.0f + 1e-8f);

    float U = 0.f;
    float vv[16];
    #pragma unroll
    for (int jj = 0; jj < 16; ++jj) vv[jj] = 0.f;

    for (int it = 0; it < MAX_ITER; ++it) {
        // w[jj] = Crow + V_j  (state after `it` iterations)
        float w[16];
        #pragma unroll
        for (int jj = 0; jj < 16; ++jj) w[jj] = Crow[jj] + vv[jj];

        // cost of state after iteration `it` (valid for it>=1 -> index it-1)
        if (it > 0) {
            float ca = 0.f;
            #pragma unroll
            for (int jj = 0; jj < 16; ++jj)
                ca = fmaf(__expf(U + w[jj]), -0.1f * Crow[jj], ca);
            #pragma unroll
            for (int m = 1; m < 64; m <<= 1) ca += __shfl_xor(ca, m);
            if (t == 0) cost_all[(size_t)(it - 1) * (2 * nE) + b] = ca;
        }

        // ---- row pass: U_new = logmu - lse_j(w) ----
        float mx = w[0];
        #pragma unroll
        for (int jj = 1; jj < 16; ++jj) mx = fmaxf(mx, w[jj]);
        mx = fmaxf(mx, __shfl_xor(mx, 32));
        float sm = 0.f;
        #pragma unroll
        for (int jj = 0; jj < 16; ++jj) sm += __expf(w[jj] - mx);
        sm += __shfl_xor(sm, 32);
        float Un = logmu - (mx + __logf(sm));

        // err = mean over edges of sum_i |u_new - u|  (u = 0.1*U)
        float du = (h == 0) ? 0.1f * fabsf(Un - U) : 0.f;
        #pragma unroll
        for (int m = 1; m < 64; m <<= 1) du += __shfl_xor(du, m);
        if (t == 0) err_part[(size_t)it * (2 * nE) + b] = du;
        U = Un;

        // ---- col pass: V_new = logmu - lse_i(Ccol + U_new) ----
        float wc[16];
        #pragma unroll
        for (int ii = 0; ii < 16; ++ii) {
            float uu = __shfl(U, r0 + ii);
            wc[ii] = Ccol[ii] + uu;
        }
        float mx2 = wc[0];
        #pragma unroll
        for (int ii = 1; ii < 16; ++ii) mx2 = fmaxf(mx2, wc[ii]);
        mx2 = fmaxf(mx2, __shfl_xor(mx2, 32));
        float sm2 = 0.f;
        #pragma unroll
        for (int ii = 0; ii < 16; ++ii) sm2 += __expf(wc[ii] - mx2);
        sm2 += __shfl_xor(sm2, 32);
        float Vn = logmu - (mx2 + __logf(sm2));
        #pragma unroll
        for (int jj = 0; jj < 16; ++jj) vv[jj] = __shfl(Vn, r0 + jj);
    }

    // cost of final state (after MAX_ITER iterations) -> index MAX_ITER-1
    {
        float ca = 0.f;
        #pragma unroll
        for (int jj = 0; jj < 16; ++jj)
            ca = fmaf(__expf(U + Crow[jj] + vv[jj]), -0.1f * Crow[jj], ca);
        #pragma unroll
        for (int m = 1; m < 64; m <<= 1) ca += __shfl_xor(ca, m);
        if (t == 0) cost_all[(size_t)(MAX_ITER - 1) * (2 * nE) + b] = ca;
    }
}

// ---------------- err reduction: 20 blocks, deterministic ----------------
__global__ __launch_bounds__(256) void err_reduce(
    const float* __restrict__ err_part, float* __restrict__ err_mean, int nE)
{
    int side = blockIdx.x / MAX_ITER;
    int it = blockIdx.x - side * MAX_ITER;
    const float* p = err_part + (size_t)it * (2 * nE) + side * nE;
    float s = 0.f;
    for (int idx = threadIdx.x; idx < nE; idx += 256) s += p[idx];
    __shared__ float red[256];
    red[threadIdx.x] = s;
    __syncthreads();
    for (int stride = 128; stride > 0; stride >>= 1) {
        if (threadIdx.x < stride) red[threadIdx.x] += red[threadIdx.x + stride];
        __syncthreads();
    }
    if (threadIdx.x == 0) err_mean[side * MAX_ITER + it] = red[0] / (float)nE;
}

// ---------------- final: pick T per side, gather costs, reduce loss -------
__global__ __launch_bounds__(256) void final_loss(
    const float* __restrict__ err_mean, const float* __restrict__ cost_all,
    float* __restrict__ out, int nE)
{
    int Tp = MAX_ITER, Tn = MAX_ITER;
    for (int it = 0; it < MAX_ITER; ++it)
        if (err_mean[it] < THRESH) { Tp = it + 1; break; }
    for (int it = 0; it < MAX_ITER; ++it)
        if (err_mean[MAX_ITER + it] < THRESH) { Tn = it + 1; break; }

    float s = 0.f;
    for (int b = threadIdx.x; b < 2 * nE; b += 256) {
        int side = (b >= nE) ? 1 : 0;
        int T = side ? Tn : Tp;
        float cost = cost_all[(size_t)(T - 1) * (2 * nE) + b];
        s += side ? expf(-cost) : cost * cost;   // exp(neg_energy) | pos^2
    }
    __shared__ float red[256];
    red[threadIdx.x] = s;
    __syncthreads();
    for (int stride = 128; stride > 0; stride >>= 1) {
        if (threadIdx.x < stride) red[threadIdx.x] += red[threadIdx.x + stride];
        __syncthreads();
    }
    if (threadIdx.x == 0) out[0] = red[0] / (float)nE;
}

extern "C" void kernel_launch(void* const* d_in, const int* in_sizes, int n_in,
                              void* d_out, int out_size, void* d_ws, size_t ws_size,
                              hipStream_t stream)
{
    const float* X = (const float*)d_in[0];
    const float* W = (const float*)d_in[1];
    const int* ep = (const int*)d_in[2];
    const int* en = (const int*)d_in[3];
    float* out = (float*)d_out;

    int K = in_sizes[1] / EMB;     // 256
    int M = in_sizes[0] / K;       // 10000
    int nE = in_sizes[2] / 2;      // 4096

    float* ws = (float*)d_ws;
    float* Z = ws;                                              // M*EMB
    float* err_part = Z + (size_t)M * EMB;                      // MAX_ITER*2nE
    float* cost_all = err_part + (size_t)MAX_ITER * 2 * nE;     // MAX_ITER*2nE
    float* err_mean = cost_all + (size_t)MAX_ITER * 2 * nE;     // 32 (20 used)

    dim3 gg((M + BM - 1) / BM, EMB / BN);
    gemm_f32<<<gg, 256, 0, stream>>>(X, W, Z, M, K, EMB);

    sinkhorn_fused<<<2 * nE, 64, 0, stream>>>(Z, ep, en, nE, err_part, cost_all);
    err_reduce<<<2 * MAX_ITER, 256, 0, stream>>>(err_part, err_mean, nE);
    final_loss<<<1, 256, 0, stream>>>(err_mean, cost_all, out, nE);
}